// Round 5
// baseline (1854.231 us; speedup 1.0000x reference)
//
#include <hip/hip_runtime.h>
#include <hip/hip_bf16.h>

#define B_ 4
#define N_ 2048
#define F_ 256
#define H_ 8
#define O_ 256

// log2(e)/16 folded into Q so softmax can use exp2f (exact softmax, monotone map)
#define SCALE_QK 0.09016844005556021f

typedef __attribute__((ext_vector_type(8))) short short8;
typedef __attribute__((ext_vector_type(4))) float f32x4;

static __device__ __forceinline__ float bf2f(short u) {
    unsigned int x = ((unsigned int)(unsigned short)u) << 16;
    return __builtin_bit_cast(float, x);
}
static __device__ __forceinline__ short f2bf(float f) {
    unsigned int x = __builtin_bit_cast(unsigned int, f);
    unsigned int lsb = (x >> 16) & 1u;
    x += 0x7fffu + lsb;
    return (short)(x >> 16);
}

// async global->LDS 16B/lane; LDS dst is wave-uniform base + lane*16
static __device__ __forceinline__ void gld16(const short* g, short* l) {
    __builtin_amdgcn_global_load_lds(
        (const __attribute__((address_space(1))) void*)g,
        (__attribute__((address_space(3))) void*)l, 16, 0, 0);
}

// ---------------- f32 -> bf16 transpose: dst[c][r] = (bf16)src[r][c] ----
__global__ __launch_bounds__(256) void cvtT_kernel(const float* __restrict__ src,
                                                   short* __restrict__ dst,
                                                   int R, int C) {
    __shared__ short tile[32][33];
    src += (size_t)blockIdx.z * R * C;
    dst += (size_t)blockIdx.z * R * C;
    int tx = threadIdx.x, ty = threadIdx.y;           // 32 x 8
    int c0 = blockIdx.x * 32, r0 = blockIdx.y * 32;
#pragma unroll
    for (int j = 0; j < 4; j++) {
        int r = r0 + ty + j * 8;
        tile[ty + j * 8][tx] = f2bf(src[(size_t)r * C + c0 + tx]);
    }
    __syncthreads();
#pragma unroll
    for (int j = 0; j < 4; j++) {
        int c = c0 + ty + j * 8;
        dst[(size_t)c * R + r0 + tx] = tile[tx][ty + j * 8];
    }
}

// ---------------- f32 -> bf16 straight convert ----------------
__global__ __launch_bounds__(256) void cvt_kernel(const float* __restrict__ src,
                                                  short* __restrict__ dst, int n) {
    int i = blockIdx.x * 256 + threadIdx.x;
    if (n >= 2048) {
        size_t base = (size_t)i * 8;
#pragma unroll
        for (int j = 0; j < 8; j++) dst[base + j] = f2bf(src[base + j]);
    } else if (i < n) {
        dst[i] = f2bf(src[i]);
    }
}

// ---- 64-row MFMA GEMM tile, B^T input: C[m][n] = sum_k A[m][k]*Bt[n][k]
template <int NCT>
__device__ __forceinline__ void gemm64_bt(const short* __restrict__ A, int lda,
                                          const short* __restrict__ Bt, int ldb,
                                          float* __restrict__ C, int ldc,
                                          int K, const short* __restrict__ bias) {
    __shared__ short sA[64][72];
    __shared__ short sB[NCT * 16][72];
    int tid = threadIdx.x;
    int w = tid >> 6, l = tid & 63, lq = l & 15, quad = l >> 4;
    f32x4 acc[NCT];
#pragma unroll
    for (int i = 0; i < NCT; i++) acc[i] = (f32x4)(0.f);

    for (int kb = 0; kb < K; kb += 64) {
        __syncthreads();
#pragma unroll
        for (int i = 0; i < 2; i++) {
            int idx = tid + i * 256; int r = idx >> 3, c = (idx & 7) * 8;
            *(short8*)&sA[r][c] = *(const short8*)&A[(size_t)r * lda + kb + c];
        }
#pragma unroll
        for (int i = 0; i < NCT / 2; i++) {
            int idx = tid + i * 256; int r = idx >> 3, c = (idx & 7) * 8;
            *(short8*)&sB[r][c] = *(const short8*)&Bt[(size_t)r * ldb + kb + c];
        }
        __syncthreads();
#pragma unroll
        for (int kk = 0; kk < 2; kk++) {
            short8 af = *(const short8*)&sA[w * 16 + lq][kk * 32 + quad * 8];
#pragma unroll
            for (int ct = 0; ct < NCT; ct++) {
                short8 bf = *(const short8*)&sB[ct * 16 + lq][kk * 32 + quad * 8];
                acc[ct] = __builtin_amdgcn_mfma_f32_16x16x32_bf16(af, bf, acc[ct], 0, 0, 0);
            }
        }
    }
#pragma unroll
    for (int ct = 0; ct < NCT; ct++) {
        int col = ct * 16 + lq;
        float bv = bias ? bf2f(bias[col]) : 0.f;
#pragma unroll
        for (int r = 0; r < 4; r++) {
            int row = w * 16 + quad * 4 + r;
            C[(size_t)row * ldc + col] = acc[ct][r] + bv;
        }
    }
}

// out[m][o] = sum_k msgs[m][k] * Wout[k][o] + bias[o]; grid (128, 2); f32 out
__global__ __launch_bounds__(256) void out_kernel(const short* __restrict__ msgs,
                                                  const short* __restrict__ WoutT,
                                                  const short* __restrict__ bias,
                                                  float* __restrict__ out) {
    int mt = blockIdx.x, nt = blockIdx.y;
    gemm64_bt<8>(msgs + (size_t)mt * 64 * (H_ * F_), H_ * F_,
                 WoutT + (size_t)nt * 128 * (H_ * F_), H_ * F_,
                 out + (size_t)mt * 64 * O_ + nt * 128, O_,
                 H_ * F_, bias + nt * 128);
}

// ============ fused flash attention ============
// Block: 128 q-rows, 4 waves, each wave M=32 (two 16-row tiles m0=w*16, m1=64+w*16).
// S^T form: A = keys (LDS, swizzled), B = Q (registers). Per-q softmax state at lane lq.
// LDS: kvf [64][256] keys (XOR b^(row&31)); kvTf [256][64] V^T (XOR b^(row&7)); plf P staging.
__global__ __launch_bounds__(256, 2) void attn_kernel(const short* __restrict__ X,
                                                      const short* __restrict__ WhT,
                                                      const short* __restrict__ XT,
                                                      short* __restrict__ msgs) {
    __shared__ short kvf[64 * 256];     // 32 KB; phase0: xq
    __shared__ short kvTf[256 * 64];    // 32 KB; phase0: W chunk, then Q bf16
    __shared__ short plf[4 * 16 * 72];  // 9 KB per-wave P staging [q 16][key 64+8]

    int qt = blockIdx.x, bh = blockIdx.y, b = bh >> 3, h = bh & 7;
    int tid = threadIdx.x, w = tid >> 6, l = tid & 63, lq = l & 15, quad = l >> 4;
    int q0 = qt * 128;

    const short* Xb  = X  + (size_t)b * N_ * F_;
    const short* XTb = XT + (size_t)b * F_ * N_;
    const short* Whh = WhT + (size_t)h * F_ * F_;

    f32x4 oacc[2][16];
    short8 aq[2][8];

    // ---------- phase 0: Q = (X @ Wh) * SCALE_QK, two 64-row halves ----------
#pragma unroll
    for (int m = 0; m < 2; m++)
#pragma unroll
        for (int i = 0; i < 16; i++) oacc[m][i] = (f32x4)(0.f);

    for (int hh = 0; hh < 2; hh++) {
        __syncthreads();   // previous half's aq reads (kvTf) + mfma reads (kvf) done
        // stage X rows [q0+hh*64 .. +63] into kvf, swizzled b^(r&31)
#pragma unroll
        for (int i = 0; i < 8; i++) {
            int r = w * 16 + i * 2 + (l >> 5);
            int bb = (l & 31) ^ (r & 31);
            gld16(&Xb[(size_t)(q0 + hh * 64 + r) * F_ + bb * 8], &kvf[(w * 16 + i * 2) * 256]);
        }
        for (int kb = 0; kb < 4; kb++) {
            __syncthreads();   // prev kb's W reads done (and xq DMA drained on kb==0)
            // stage WhT[h][256][kb*64..+63] into kvTf, swizzled b^(r&7)
#pragma unroll
            for (int i = 0; i < 8; i++) {
                int r = w * 64 + i * 8 + (l >> 3);
                int bb = (l & 7) ^ (r & 7);
                gld16(&Whh[(size_t)r * F_ + kb * 64 + bb * 8], &kvTf[(w * 64 + i * 8) * 64]);
            }
            __syncthreads();
#pragma unroll
            for (int kk = 0; kk < 2; kk++) {
                int arow = w * 16 + lq;
                int ab = (kb * 8 + kk * 4 + quad) ^ (arow & 31);
                short8 af = *(const short8*)&kvf[arow * 256 + ab * 8];
#pragma unroll
                for (int ct = 0; ct < 16; ct++) {
                    int brow = ct * 16 + lq;
                    int bb = (kk * 4 + quad) ^ (brow & 7);
                    short8 bf = *(const short8*)&kvTf[brow * 64 + bb * 8];
                    oacc[hh][ct] = __builtin_amdgcn_mfma_f32_16x16x32_bf16(af, bf, oacc[hh][ct], 0, 0, 0);
                }
            }
        }
        __syncthreads();   // all W reads done; reuse kvTf as Q bf16 [64][256] swizzled b^(r&31)
#pragma unroll
        for (int ct = 0; ct < 16; ct++) {
#pragma unroll
            for (int r = 0; r < 4; r++) {
                int row = w * 16 + quad * 4 + r;
                int col = ct * 16 + lq;
                int pb = ((col >> 3) ^ (row & 31));
                kvTf[row * 256 + pb * 8 + (col & 7)] = f2bf(oacc[hh][ct][r] * SCALE_QK);
            }
        }
        __syncthreads();
        // aq[hh][kk]: B-frag = Q[q=w*16+lq][kk*32+quad*8..+7]
#pragma unroll
        for (int kk = 0; kk < 8; kk++) {
            int row = w * 16 + lq;
            int ab = (kk * 4 + quad) ^ (row & 31);
            aq[hh][kk] = *(const short8*)&kvTf[row * 256 + ab * 8];
        }
    }

    // ---------- phase 1: flash attention, BN=64 keys/iter ----------
#pragma unroll
    for (int m = 0; m < 2; m++)
#pragma unroll
        for (int i = 0; i < 16; i++) oacc[m][i] = (f32x4)(0.f);
    float m_q[2] = {-INFINITY, -INFINITY};   // per-q (q = m*64 + w*16 + lq)
    float l_q[2] = {0.f, 0.f};

    for (int kt = 0; kt < N_ / 64; kt++) {
        __syncthreads();   // prev iter reads + aq loads (kt==0) done
#pragma unroll
        for (int i = 0; i < 8; i++) {
            int rk = w * 16 + i * 2 + (l >> 5);
            int bk = (l & 31) ^ (rk & 31);
            gld16(&Xb[(size_t)(kt * 64 + rk) * F_ + bk * 8], &kvf[(w * 16 + i * 2) * 256]);
            int rt = w * 64 + i * 8 + (l >> 3);
            int bt = (l & 7) ^ (rt & 7);
            gld16(&XTb[(size_t)rt * N_ + kt * 64 + bt * 8], &kvTf[(w * 64 + i * 8) * 64]);
        }
        __syncthreads();

        // S^T tiles: sacc[m][ct] = D[key = ct*16+quad*4+r][q = lq] for q-tile m
        f32x4 sacc[2][4];
#pragma unroll
        for (int m = 0; m < 2; m++)
#pragma unroll
            for (int ct = 0; ct < 4; ct++) sacc[m][ct] = (f32x4)(0.f);
#pragma unroll
        for (int kk = 0; kk < 8; kk++) {
#pragma unroll
            for (int ct = 0; ct < 4; ct++) {
                int arow = ct * 16 + lq;
                int ab = (kk * 4 + quad) ^ (arow & 31);
                short8 af = *(const short8*)&kvf[arow * 256 + ab * 8];
                sacc[0][ct] = __builtin_amdgcn_mfma_f32_16x16x32_bf16(af, aq[0][kk], sacc[0][ct], 0, 0, 0);
                sacc[1][ct] = __builtin_amdgcn_mfma_f32_16x16x32_bf16(af, aq[1][kk], sacc[1][ct], 0, 0, 0);
            }
        }

        // online softmax in q-space (state at lane lq; lane's 16 values per m span all 64 keys across quads)
        float alpha[2];
#pragma unroll
        for (int m = 0; m < 2; m++) {
            float mx = -INFINITY;
#pragma unroll
            for (int ct = 0; ct < 4; ct++)
#pragma unroll
                for (int r = 0; r < 4; r++) mx = fmaxf(mx, sacc[m][ct][r]);
            mx = fmaxf(mx, __shfl_xor(mx, 16));
            mx = fmaxf(mx, __shfl_xor(mx, 32));
            float mn = fmaxf(m_q[m], mx);
            alpha[m] = exp2f(m_q[m] - mn);
            m_q[m] = mn;
        }
        if (!__all(alpha[0] == 1.0f && alpha[1] == 1.0f)) {
#pragma unroll
            for (int m = 0; m < 2; m++)
#pragma unroll
                for (int r = 0; r < 4; r++) {
                    float ar = __shfl(alpha[m], quad * 4 + r);
#pragma unroll
                    for (int ct = 0; ct < 16; ct++) oacc[m][ct][r] *= ar;
                }
        }

        // P = exp2(S - m), store P^T value to pl[q=lq][key], read back as A-frags
        short8 pa[2][2];
#pragma unroll
        for (int m = 0; m < 2; m++) {
            float s = 0.f;
#pragma unroll
            for (int ct = 0; ct < 4; ct++)
#pragma unroll
                for (int r = 0; r < 4; r++) {
                    float pv = exp2f(sacc[m][ct][r] - m_q[m]);
                    s += pv;
                    plf[(w * 16 + lq) * 72 + ct * 16 + quad * 4 + r] = f2bf(pv);
                }
            s += __shfl_xor(s, 16);
            s += __shfl_xor(s, 32);
            l_q[m] = l_q[m] * alpha[m] + s;
            pa[m][0] = *(const short8*)&plf[(w * 16 + lq) * 72 + quad * 8];
            pa[m][1] = *(const short8*)&plf[(w * 16 + lq) * 72 + 32 + quad * 8];
        }

        // O += P @ V : B-frags from kvTf (V^T), shared across both m
#pragma unroll
        for (int ct = 0; ct < 16; ct++) {
            int brow = ct * 16 + lq;
            short8 b0 = *(const short8*)&kvTf[brow * 64 + ((quad) ^ (brow & 7)) * 8];
            short8 b1 = *(const short8*)&kvTf[brow * 64 + ((4 + quad) ^ (brow & 7)) * 8];
            oacc[0][ct] = __builtin_amdgcn_mfma_f32_16x16x32_bf16(pa[0][0], b0, oacc[0][ct], 0, 0, 0);
            oacc[0][ct] = __builtin_amdgcn_mfma_f32_16x16x32_bf16(pa[0][1], b1, oacc[0][ct], 0, 0, 0);
            oacc[1][ct] = __builtin_amdgcn_mfma_f32_16x16x32_bf16(pa[1][0], b0, oacc[1][ct], 0, 0, 0);
            oacc[1][ct] = __builtin_amdgcn_mfma_f32_16x16x32_bf16(pa[1][1], b1, oacc[1][ct], 0, 0, 0);
        }
    }

    // epilogue: normalize rows, write msgs[b*N + q][h*F + f]
#pragma unroll
    for (int m = 0; m < 2; m++) {
        float inv = 1.f / l_q[m];
        short* Mout = msgs + ((size_t)(b * N_ + q0 + m * 64 + w * 16)) * (H_ * F_) + h * F_;
#pragma unroll
        for (int r = 0; r < 4; r++) {
            float invr = __shfl(inv, quad * 4 + r);
            int row = quad * 4 + r;
#pragma unroll
            for (int ct = 0; ct < 16; ct++)
                Mout[(size_t)row * (H_ * F_) + ct * 16 + lq] = f2bf(oacc[m][ct][r] * invr);
        }
    }
}

extern "C" void kernel_launch(void* const* d_in, const int* in_sizes, int n_in,
                              void* d_out, int out_size, void* d_ws, size_t ws_size,
                              hipStream_t stream) {
    const float* nodes = (const float*)d_in[0];   // [4,2048,256] f32
    const float* Wh    = (const float*)d_in[1];   // [8,256,256]  f32
    const float* Wout  = (const float*)d_in[2];   // [2048,256]   f32
    const float* bias  = (const float*)d_in[3];   // [256]        f32
    float* out = (float*)d_out;                   // [4,2048,256] f32

    char* ws = (char*)d_ws;
    short* msgs   = (short*)(ws);                   // [8192][2048] bf16 = 32 MB
    short* WhT    = (short*)(ws + 33554432);        // [8][256][256]       1 MB
    short* WoutT  = (short*)(ws + 34603008);        // [256][2048]         1 MB
    short* XT     = (short*)(ws + 35651584);        // [4][256][2048]      4 MB
    short* Xbf    = (short*)(ws + 39845888);        // [4][2048][256]      4 MB
    short* biasbf = (short*)(ws + 44040192);        // [256]

    dim3 tblk(32, 8, 1);
    hipLaunchKernelGGL(cvtT_kernel, dim3(8, 8, 8),  tblk, 0, stream, Wh,    WhT,   256,  256);
    hipLaunchKernelGGL(cvtT_kernel, dim3(8, 64, 1), tblk, 0, stream, Wout,  WoutT, 2048, 256);
    hipLaunchKernelGGL(cvtT_kernel, dim3(8, 64, 4), tblk, 0, stream, nodes, XT,    2048, 256);
    hipLaunchKernelGGL(cvt_kernel,  dim3(1024), dim3(256), 0, stream, nodes, Xbf, 2097152);
    hipLaunchKernelGGL(cvt_kernel,  dim3(1),    dim3(256), 0, stream, bias, biasbf, 256);

    hipLaunchKernelGGL(attn_kernel, dim3(16, 32), dim3(256), 0, stream, Xbf, WhT, XT, msgs);
    hipLaunchKernelGGL(out_kernel,  dim3(128, 2), dim3(256), 0, stream, msgs, WoutT, biasbf, out);
}

// Round 7
// 489.412 us; speedup vs baseline: 3.7887x; 3.7887x over previous
//
#include <hip/hip_runtime.h>
#include <hip/hip_bf16.h>

#define B_ 4
#define N_ 2048
#define F_ 256
#define H_ 8
#define O_ 256

// log2(e)/16 folded into Q so softmax can use exp2f (exact softmax, monotone map)
#define SCALE_QK 0.09016844005556021f

typedef __attribute__((ext_vector_type(8))) short short8;
typedef __attribute__((ext_vector_type(4))) short s16x4;
typedef __attribute__((ext_vector_type(4))) float f32x4;
typedef __attribute__((ext_vector_type(4))) unsigned int u32x4;

static __device__ __forceinline__ float bf2f(short u) {
    unsigned int x = ((unsigned int)(unsigned short)u) << 16;
    return __builtin_bit_cast(float, x);
}
static __device__ __forceinline__ short f2bf(float f) {
    unsigned int x = __builtin_bit_cast(unsigned int, f);
    unsigned int lsb = (x >> 16) & 1u;
    x += 0x7fffu + lsb;
    return (short)(x >> 16);
}
static __device__ __forceinline__ unsigned int pkbf(float a, float b) {
    return (unsigned int)(unsigned short)f2bf(a) |
           ((unsigned int)(unsigned short)f2bf(b) << 16);
}

// async global->LDS 16B/lane; LDS dst is wave-uniform base + lane*16
static __device__ __forceinline__ void gld16(const short* g, short* l) {
    __builtin_amdgcn_global_load_lds(
        (const __attribute__((address_space(1))) void*)g,
        (__attribute__((address_space(3))) void*)l, 16, 0, 0);
}

// ---------------- f32 -> bf16 transpose: dst[c][r] = (bf16)src[r][c] ----
__global__ __launch_bounds__(256) void cvtT_kernel(const float* __restrict__ src,
                                                   short* __restrict__ dst,
                                                   int R, int C) {
    __shared__ short tile[32][33];
    src += (size_t)blockIdx.z * R * C;
    dst += (size_t)blockIdx.z * R * C;
    int tx = threadIdx.x, ty = threadIdx.y;           // 32 x 8
    int c0 = blockIdx.x * 32, r0 = blockIdx.y * 32;
#pragma unroll
    for (int j = 0; j < 4; j++) {
        int r = r0 + ty + j * 8;
        tile[ty + j * 8][tx] = f2bf(src[(size_t)r * C + c0 + tx]);
    }
    __syncthreads();
#pragma unroll
    for (int j = 0; j < 4; j++) {
        int c = c0 + ty + j * 8;
        dst[(size_t)c * R + r0 + tx] = tile[tx][ty + j * 8];
    }
}

// ---------------- f32 -> bf16 straight convert ----------------
__global__ __launch_bounds__(256) void cvt_kernel(const float* __restrict__ src,
                                                  short* __restrict__ dst, int n) {
    int i = blockIdx.x * 256 + threadIdx.x;
    if (n >= 2048) {
        size_t base = (size_t)i * 8;
#pragma unroll
        for (int j = 0; j < 8; j++) dst[base + j] = f2bf(src[base + j]);
    } else if (i < n) {
        dst[i] = f2bf(src[i]);
    }
}

// ---- 64-row MFMA GEMM tile, B^T input: C[m][n] = sum_k A[m][k]*Bt[n][k]
template <int NCT>
__device__ __forceinline__ void gemm64_bt(const short* __restrict__ A, int lda,
                                          const short* __restrict__ Bt, int ldb,
                                          float* __restrict__ C, int ldc,
                                          int K, const short* __restrict__ bias) {
    __shared__ short sA[64][72];
    __shared__ short sB[NCT * 16][72];
    int tid = threadIdx.x;
    int w = tid >> 6, l = tid & 63, lq = l & 15, quad = l >> 4;
    f32x4 acc[NCT];
#pragma unroll
    for (int i = 0; i < NCT; i++) acc[i] = (f32x4)(0.f);

    for (int kb = 0; kb < K; kb += 64) {
        __syncthreads();
#pragma unroll
        for (int i = 0; i < 2; i++) {
            int idx = tid + i * 256; int r = idx >> 3, c = (idx & 7) * 8;
            *(short8*)&sA[r][c] = *(const short8*)&A[(size_t)r * lda + kb + c];
        }
#pragma unroll
        for (int i = 0; i < NCT / 2; i++) {
            int idx = tid + i * 256; int r = idx >> 3, c = (idx & 7) * 8;
            *(short8*)&sB[r][c] = *(const short8*)&Bt[(size_t)r * ldb + kb + c];
        }
        __syncthreads();
#pragma unroll
        for (int kk = 0; kk < 2; kk++) {
            short8 af = *(const short8*)&sA[w * 16 + lq][kk * 32 + quad * 8];
#pragma unroll
            for (int ct = 0; ct < NCT; ct++) {
                short8 bf = *(const short8*)&sB[ct * 16 + lq][kk * 32 + quad * 8];
                acc[ct] = __builtin_amdgcn_mfma_f32_16x16x32_bf16(af, bf, acc[ct], 0, 0, 0);
            }
        }
    }
#pragma unroll
    for (int ct = 0; ct < NCT; ct++) {
        int col = ct * 16 + lq;
        float bv = bias ? bf2f(bias[col]) : 0.f;
#pragma unroll
        for (int r = 0; r < 4; r++) {
            int row = w * 16 + quad * 4 + r;
            C[(size_t)row * ldc + col] = acc[ct][r] + bv;
        }
    }
}

// out[m][o] = msgs[m][:] @ Wout + bias; grid (128,4) = 512 blocks -> 2/CU
__global__ __launch_bounds__(256) void out_kernel(const short* __restrict__ msgs,
                                                  const short* __restrict__ WoutT,
                                                  const short* __restrict__ bias,
                                                  float* __restrict__ out) {
    int mt = blockIdx.x, nt = blockIdx.y;
    gemm64_bt<4>(msgs + (size_t)mt * 64 * (H_ * F_), H_ * F_,
                 WoutT + (size_t)nt * 64 * (H_ * F_), H_ * F_,
                 out + (size_t)mt * 64 * O_ + nt * 64, O_,
                 H_ * F_, bias + nt * 64);
}

// ============ fused flash attention ============
// Block: 64 q (4 waves x 16 q), BN=64 keys/iter. S^T form: S^T = K·Q^T
// (A = keys from LDS, B = Q in registers), O^T = V^T·P^T (A = V^T from LDS,
// B = P^T built by register shuffles). Softmax state per-lane at q = lq.
// LDS = exactly 64 KB -> 2 blocks/CU co-resident.
__global__ __launch_bounds__(256) void attn_kernel(const short* __restrict__ X,
                                                   const short* __restrict__ WhT,
                                                   const short* __restrict__ XT,
                                                   short* __restrict__ msgs) {
    __shared__ short kvf[64 * 256];     // 32 KB: K tile [key][feat], XOR b^(r&31); phase0: X q-tile
    __shared__ short kvTf[256 * 64];    // 32 KB: V^T [feat][key], XOR b^(r&7); phase0: W chunk, then Q

    int qt = blockIdx.x, bh = blockIdx.y, b = bh >> 3, h = bh & 7;
    int tid = threadIdx.x, w = tid >> 6, l = tid & 63, lq = l & 15, quad = l >> 4;
    int q0 = qt * 64;

    const short* Xb  = X  + (size_t)b * N_ * F_;
    const short* XTb = XT + (size_t)b * F_ * N_;
    const short* Whh = WhT + (size_t)h * F_ * F_;

    f32x4 oacc[16];
    short8 aq[8];

    // ---------- phase 0: Q = (X qtile @ Wh) * SCALE_QK ----------
#pragma unroll
    for (int i = 0; i < 16; i++) oacc[i] = (f32x4)(0.f);
    // stage X rows [q0 .. q0+63] into kvf, swizzled b^(r&31)
#pragma unroll
    for (int i = 0; i < 8; i++) {
        int r = w * 16 + i * 2 + (l >> 5);
        int bb = (l & 31) ^ (r & 31);
        gld16(&Xb[(size_t)(q0 + r) * F_ + bb * 8], &kvf[(w * 16 + i * 2) * 256]);
    }
    for (int kb = 0; kb < 4; kb++) {
        __syncthreads();   // prev kb's W reads done; (kb==0: no-op ordering)
#pragma unroll
        for (int i = 0; i < 8; i++) {     // stage WhT[h][0:256][kb*64..+63] into kvTf
            int r = w * 64 + i * 8 + (l >> 3);
            int bb = (l & 7) ^ (r & 7);
            gld16(&Whh[(size_t)r * F_ + kb * 64 + bb * 8], &kvTf[(w * 64 + i * 8) * 64]);
        }
        __syncthreads();   // drains DMA -> kvf (kb==0) + kvTf ready
#pragma unroll
        for (int kk = 0; kk < 2; kk++) {
            int arow = w * 16 + lq;
            int ab = (kb * 8 + kk * 4 + quad) ^ (arow & 31);
            short8 af = *(const short8*)&kvf[arow * 256 + ab * 8];
#pragma unroll
            for (int ct = 0; ct < 16; ct++) {
                int brow = ct * 16 + lq;
                int bb = (kk * 4 + quad) ^ (brow & 7);
                short8 bf = *(const short8*)&kvTf[brow * 64 + bb * 8];
                oacc[ct] = __builtin_amdgcn_mfma_f32_16x16x32_bf16(af, bf, oacc[ct], 0, 0, 0);
            }
        }
    }
    __syncthreads();   // all W reads done; reuse kvTf as Q [64 q][256 f], swizzled b^(r&31)
#pragma unroll
    for (int ct = 0; ct < 16; ct++) {
#pragma unroll
        for (int r = 0; r < 4; r++) {
            int row = w * 16 + quad * 4 + r;
            int col = ct * 16 + lq;
            int pb = (col >> 3) ^ (row & 31);
            kvTf[row * 256 + pb * 8 + (col & 7)] = f2bf(oacc[ct][r] * SCALE_QK);
        }
    }
    __syncthreads();
    // aq[kk]: B-frag Q[q = w*16+lq][kk*32 + quad*8 ..+7]
#pragma unroll
    for (int kk = 0; kk < 8; kk++) {
        int row = w * 16 + lq;
        int ab = (kk * 4 + quad) ^ (row & 31);
        aq[kk] = *(const short8*)&kvTf[row * 256 + ab * 8];
    }

    // ---------- phase 1: flash attention ----------
#pragma unroll
    for (int i = 0; i < 16; i++) oacc[i] = (f32x4)(0.f);
    float m_q = -INFINITY, l_q = 0.f;   // state for q = q0 + w*16 + lq

    for (int kt = 0; kt < N_ / 64; kt++) {
        __syncthreads();   // prev iter reads + aq loads (kt==0) done
#pragma unroll
        for (int i = 0; i < 8; i++) {
            int rk = w * 16 + i * 2 + (l >> 5);
            int bk = (l & 31) ^ (rk & 31);
            gld16(&Xb[(size_t)(kt * 64 + rk) * F_ + bk * 8], &kvf[(w * 16 + i * 2) * 256]);
            int rt = w * 64 + i * 8 + (l >> 3);
            int bt = (l & 7) ^ (rt & 7);
            gld16(&XTb[(size_t)rt * N_ + kt * 64 + bt * 8], &kvTf[(w * 64 + i * 8) * 64]);
        }
        __syncthreads();   // DMA drained

        // S^T: sacc[ct] = S^T[key = ct*16+quad*4+r][q = lq]
        f32x4 sacc[4];
#pragma unroll
        for (int ct = 0; ct < 4; ct++) sacc[ct] = (f32x4)(0.f);
#pragma unroll
        for (int kk = 0; kk < 8; kk++) {
#pragma unroll
            for (int ct = 0; ct < 4; ct++) {
                int arow = ct * 16 + lq;
                int ab = (kk * 4 + quad) ^ (arow & 31);
                short8 af = *(const short8*)&kvf[arow * 256 + ab * 8];
                sacc[ct] = __builtin_amdgcn_mfma_f32_16x16x32_bf16(af, aq[kk], sacc[ct], 0, 0, 0);
            }
        }

        // online softmax, per-lane state (reduce over quads: xor 16, 32)
        float mx = -INFINITY;
#pragma unroll
        for (int ct = 0; ct < 4; ct++)
#pragma unroll
            for (int r = 0; r < 4; r++) mx = fmaxf(mx, sacc[ct][r]);
        mx = fmaxf(mx, __shfl_xor(mx, 16));
        mx = fmaxf(mx, __shfl_xor(mx, 32));
        float mn = fmaxf(m_q, mx);
        float alpha = exp2f(m_q - mn);
        m_q = mn;

        float pv[4][4]; float s = 0.f;
#pragma unroll
        for (int ct = 0; ct < 4; ct++)
#pragma unroll
            for (int r = 0; r < 4; r++) {
                pv[ct][r] = exp2f(sacc[ct][r] - mn);
                s += pv[ct][r];
            }
        s += __shfl_xor(s, 16);
        s += __shfl_xor(s, 32);
        l_q = l_q * alpha + s;
        if (!__all(alpha == 1.0f)) {
#pragma unroll
            for (int ct = 0; ct < 16; ct++)
#pragma unroll
                for (int r = 0; r < 4; r++) oacc[ct][r] *= alpha;
        }

        // pack P (bf16 pairs) and build P^T B-frags by register shuffles.
        // target lane (lq,quad), chunk kk needs P^T[key=kk*32+quad*8+j][q=lq]:
        // sources = lanes (2*(quad&1)+{0,1})*16+lq, word index ct' = 2kk+(quad>>1).
        unsigned int w2[4][2];
#pragma unroll
        for (int ct = 0; ct < 4; ct++) {
            w2[ct][0] = pkbf(pv[ct][0], pv[ct][1]);
            w2[ct][1] = pkbf(pv[ct][2], pv[ct][3]);
        }
        int sl0 = (2 * (quad & 1)) * 16 + lq;
        int sl1 = sl0 + 16;
        bool hi = (quad >> 1) != 0;
        short8 pfrag[2];
#pragma unroll
        for (int kk = 0; kk < 2; kk++) {
            unsigned int u0 = __shfl((int)w2[2 * kk][0], sl0);
            unsigned int u1 = __shfl((int)w2[2 * kk][1], sl0);
            unsigned int u2 = __shfl((int)w2[2 * kk][0], sl1);
            unsigned int u3 = __shfl((int)w2[2 * kk][1], sl1);
            unsigned int v0 = __shfl((int)w2[2 * kk + 1][0], sl0);
            unsigned int v1 = __shfl((int)w2[2 * kk + 1][1], sl0);
            unsigned int v2 = __shfl((int)w2[2 * kk + 1][0], sl1);
            unsigned int v3 = __shfl((int)w2[2 * kk + 1][1], sl1);
            u32x4 pk = { hi ? v0 : u0, hi ? v1 : u1, hi ? v2 : u2, hi ? v3 : u3 };
            pfrag[kk] = __builtin_bit_cast(short8, pk);
        }

        // O^T += V^T @ P^T : oacc[ct] = O^T[feat = ct*16+quad*4+r][q = lq]
#pragma unroll
        for (int ct = 0; ct < 16; ct++) {
            int arow = ct * 16 + lq;
            short8 a0 = *(const short8*)&kvTf[arow * 64 + ((quad) ^ (arow & 7)) * 8];
            short8 a1 = *(const short8*)&kvTf[arow * 64 + ((4 + quad) ^ (arow & 7)) * 8];
            oacc[ct] = __builtin_amdgcn_mfma_f32_16x16x32_bf16(a0, pfrag[0], oacc[ct], 0, 0, 0);
            oacc[ct] = __builtin_amdgcn_mfma_f32_16x16x32_bf16(a1, pfrag[1], oacc[ct], 0, 0, 0);
        }
    }

    // epilogue: per-lane q = q0 + w*16 + lq; feats ct*16 + quad*4 + r
    float inv = 1.f / l_q;
    short* Mout = msgs + (size_t)(b * N_ + q0 + w * 16 + lq) * (H_ * F_) + h * F_;
#pragma unroll
    for (int ct = 0; ct < 16; ct++) {
        s16x4 v4 = { f2bf(oacc[ct][0] * inv), f2bf(oacc[ct][1] * inv),
                     f2bf(oacc[ct][2] * inv), f2bf(oacc[ct][3] * inv) };
        *(s16x4*)&Mout[ct * 16 + quad * 4] = v4;
    }
}

extern "C" void kernel_launch(void* const* d_in, const int* in_sizes, int n_in,
                              void* d_out, int out_size, void* d_ws, size_t ws_size,
                              hipStream_t stream) {
    const float* nodes = (const float*)d_in[0];   // [4,2048,256] f32
    const float* Wh    = (const float*)d_in[1];   // [8,256,256]  f32
    const float* Wout  = (const float*)d_in[2];   // [2048,256]   f32
    const float* bias  = (const float*)d_in[3];   // [256]        f32
    float* out = (float*)d_out;                   // [4,2048,256] f32

    char* ws = (char*)d_ws;
    short* msgs   = (short*)(ws);                   // [8192][2048] bf16 = 32 MB
    short* WhT    = (short*)(ws + 33554432);        // [8][256][256]       1 MB
    short* WoutT  = (short*)(ws + 34603008);        // [256][2048]         1 MB
    short* XT     = (short*)(ws + 35651584);        // [4][256][2048]      4 MB
    short* Xbf    = (short*)(ws + 39845888);        // [4][2048][256]      4 MB
    short* biasbf = (short*)(ws + 44040192);        // [256]

    dim3 tblk(32, 8, 1);
    hipLaunchKernelGGL(cvtT_kernel, dim3(8, 8, 8),  tblk, 0, stream, Wh,    WhT,   256,  256);
    hipLaunchKernelGGL(cvtT_kernel, dim3(8, 64, 1), tblk, 0, stream, Wout,  WoutT, 2048, 256);
    hipLaunchKernelGGL(cvtT_kernel, dim3(8, 64, 4), tblk, 0, stream, nodes, XT,    2048, 256);
    hipLaunchKernelGGL(cvt_kernel,  dim3(1024), dim3(256), 0, stream, nodes, Xbf, 2097152);
    hipLaunchKernelGGL(cvt_kernel,  dim3(1),    dim3(256), 0, stream, bias, biasbf, 256);

    hipLaunchKernelGGL(attn_kernel, dim3(32, 32), dim3(256), 0, stream, Xbf, WhT, XT, msgs);
    hipLaunchKernelGGL(out_kernel,  dim3(128, 4), dim3(256), 0, stream, msgs, WoutT, biasbf, out);
}

// Round 8
// 295.537 us; speedup vs baseline: 6.2741x; 1.6560x over previous
//
#include <hip/hip_runtime.h>
#include <hip/hip_bf16.h>

#define B_ 4
#define N_ 2048
#define F_ 256
#define H_ 8
#define O_ 256

// log2(e)/16 folded into Q so softmax can use exp2f (exact softmax, monotone map)
#define SCALE_QK 0.09016844005556021f

typedef __attribute__((ext_vector_type(8))) short short8;
typedef __attribute__((ext_vector_type(4))) short s16x4;
typedef __attribute__((ext_vector_type(4))) float f32x4;
typedef __attribute__((ext_vector_type(4))) unsigned int u32x4;

static __device__ __forceinline__ float bf2f(short u) {
    unsigned int x = ((unsigned int)(unsigned short)u) << 16;
    return __builtin_bit_cast(float, x);
}
static __device__ __forceinline__ short f2bf(float f) {
    unsigned int x = __builtin_bit_cast(unsigned int, f);
    unsigned int lsb = (x >> 16) & 1u;
    x += 0x7fffu + lsb;
    return (short)(x >> 16);
}
static __device__ __forceinline__ unsigned int pkbf(float a, float b) {
    return (unsigned int)(unsigned short)f2bf(a) |
           ((unsigned int)(unsigned short)f2bf(b) << 16);
}

// async global->LDS 16B/lane; LDS dst is wave-uniform base + lane*16
static __device__ __forceinline__ void gld16(const short* g, short* l) {
    __builtin_amdgcn_global_load_lds(
        (const __attribute__((address_space(1))) void*)g,
        (__attribute__((address_space(3))) void*)l, 16, 0, 0);
}

// ---------------- f32 -> bf16 transpose: dst[c][r] = (bf16)src[r][c] ----
__global__ __launch_bounds__(256) void cvtT_kernel(const float* __restrict__ src,
                                                   short* __restrict__ dst,
                                                   int R, int C) {
    __shared__ short tile[32][33];
    src += (size_t)blockIdx.z * R * C;
    dst += (size_t)blockIdx.z * R * C;
    int tx = threadIdx.x, ty = threadIdx.y;           // 32 x 8
    int c0 = blockIdx.x * 32, r0 = blockIdx.y * 32;
#pragma unroll
    for (int j = 0; j < 4; j++) {
        int r = r0 + ty + j * 8;
        tile[ty + j * 8][tx] = f2bf(src[(size_t)r * C + c0 + tx]);
    }
    __syncthreads();
#pragma unroll
    for (int j = 0; j < 4; j++) {
        int c = c0 + ty + j * 8;
        dst[(size_t)c * R + r0 + tx] = tile[tx][ty + j * 8];
    }
}

// ---------------- f32 -> bf16 straight convert ----------------
__global__ __launch_bounds__(256) void cvt_kernel(const float* __restrict__ src,
                                                  short* __restrict__ dst, int n) {
    int i = blockIdx.x * 256 + threadIdx.x;
    if (n >= 2048) {
        size_t base = (size_t)i * 8;
#pragma unroll
        for (int j = 0; j < 8; j++) dst[base + j] = f2bf(src[base + j]);
    } else if (i < n) {
        dst[i] = f2bf(src[i]);
    }
}

// ---- 64-row MFMA GEMM tile, B^T input: C[m][n] = sum_k A[m][k]*Bt[n][k]
template <int NCT>
__device__ __forceinline__ void gemm64_bt(const short* __restrict__ A, int lda,
                                          const short* __restrict__ Bt, int ldb,
                                          float* __restrict__ C, int ldc,
                                          int K, const short* __restrict__ bias) {
    __shared__ short sA[64][72];
    __shared__ short sB[NCT * 16][72];
    int tid = threadIdx.x;
    int w = tid >> 6, l = tid & 63, lq = l & 15, quad = l >> 4;
    f32x4 acc[NCT];
#pragma unroll
    for (int i = 0; i < NCT; i++) acc[i] = (f32x4)(0.f);

    for (int kb = 0; kb < K; kb += 64) {
        __syncthreads();
#pragma unroll
        for (int i = 0; i < 2; i++) {
            int idx = tid + i * 256; int r = idx >> 3, c = (idx & 7) * 8;
            *(short8*)&sA[r][c] = *(const short8*)&A[(size_t)r * lda + kb + c];
        }
#pragma unroll
        for (int i = 0; i < NCT / 2; i++) {
            int idx = tid + i * 256; int r = idx >> 3, c = (idx & 7) * 8;
            *(short8*)&sB[r][c] = *(const short8*)&Bt[(size_t)r * ldb + kb + c];
        }
        __syncthreads();
#pragma unroll
        for (int kk = 0; kk < 2; kk++) {
            short8 af = *(const short8*)&sA[w * 16 + lq][kk * 32 + quad * 8];
#pragma unroll
            for (int ct = 0; ct < NCT; ct++) {
                short8 bf = *(const short8*)&sB[ct * 16 + lq][kk * 32 + quad * 8];
                acc[ct] = __builtin_amdgcn_mfma_f32_16x16x32_bf16(af, bf, acc[ct], 0, 0, 0);
            }
        }
    }
#pragma unroll
    for (int ct = 0; ct < NCT; ct++) {
        int col = ct * 16 + lq;
        float bv = bias ? bf2f(bias[col]) : 0.f;
#pragma unroll
        for (int r = 0; r < 4; r++) {
            int row = w * 16 + quad * 4 + r;
            C[(size_t)row * ldc + col] = acc[ct][r] + bv;
        }
    }
}

// out[m][o] = msgs[m][:] @ Wout + bias; grid (128,4) = 512 blocks -> 2/CU
__global__ __launch_bounds__(256) void out_kernel(const short* __restrict__ msgs,
                                                  const short* __restrict__ WoutT,
                                                  const short* __restrict__ bias,
                                                  float* __restrict__ out) {
    int mt = blockIdx.x, nt = blockIdx.y;
    gemm64_bt<4>(msgs + (size_t)mt * 64 * (H_ * F_), H_ * F_,
                 WoutT + (size_t)nt * 64 * (H_ * F_), H_ * F_,
                 out + (size_t)mt * 64 * O_ + nt * 64, O_,
                 H_ * F_, bias + nt * 64);
}

// ============ fused flash attention, double-buffered pipeline ============
// Block: 512 threads = 8 waves, 128 q (wave w owns q = q0 + w*16 + lq).
// BN=64 keys/iter. S^T = K·Q^T (A = keys from LDS, B = Q regs);
// O^T = V^T·P^T (A = V^T from LDS, B = P^T via register shuffles).
// Two static LDS buffer pairs; per kt: prefetch(next -> other pair) via
// global_load_lds, compute(current pair), ONE barrier (drains a prefetch
// issued a full compute-phase earlier). LDS = 128 KB -> 1 block/CU.

// stage key-tile KT: K rows into KVF [64][256] (XOR b^(r&31)),
// V^T rows into KVTF [256][64] (XOR b^(r&7)); 8 waves, 8 gld16/lane.
#define STAGE_KV(KT, KVF, KVTF) do {                                         \
    _Pragma("unroll")                                                        \
    for (int i_ = 0; i_ < 4; i_++) {                                         \
        int rk_ = w * 8 + i_ * 2 + (l >> 5);                                 \
        int bk_ = (l & 31) ^ (rk_ & 31);                                     \
        gld16(&Xb[(size_t)((KT) * 64 + rk_) * F_ + bk_ * 8],                 \
              &KVF[(w * 8 + i_ * 2) * 256]);                                 \
        int rt_ = w * 32 + i_ * 8 + (l >> 3);                                \
        int bt_ = (l & 7) ^ (rt_ & 7);                                       \
        gld16(&XTb[(size_t)rt_ * N_ + (KT) * 64 + bt_ * 8],                  \
              &KVTF[(w * 32 + i_ * 8) * 64]);                                \
    }                                                                        \
} while (0)

#define COMPUTE_KT(KVF, KVTF) do {                                           \
    f32x4 sacc[4];                                                           \
    _Pragma("unroll")                                                        \
    for (int ct = 0; ct < 4; ct++) sacc[ct] = (f32x4)(0.f);                  \
    _Pragma("unroll")                                                        \
    for (int kk = 0; kk < 8; kk++) {                                         \
        _Pragma("unroll")                                                    \
        for (int ct = 0; ct < 4; ct++) {                                     \
            int arow = ct * 16 + lq;                                         \
            int ab = (kk * 4 + quad) ^ (arow & 31);                          \
            short8 af = *(const short8*)&KVF[arow * 256 + ab * 8];           \
            sacc[ct] = __builtin_amdgcn_mfma_f32_16x16x32_bf16(af, aq[kk], sacc[ct], 0, 0, 0); \
        }                                                                    \
    }                                                                        \
    float mx = -INFINITY;                                                    \
    _Pragma("unroll")                                                        \
    for (int ct = 0; ct < 4; ct++)                                           \
        _Pragma("unroll")                                                    \
        for (int r_ = 0; r_ < 4; r_++) mx = fmaxf(mx, sacc[ct][r_]);         \
    mx = fmaxf(mx, __shfl_xor(mx, 16));                                      \
    mx = fmaxf(mx, __shfl_xor(mx, 32));                                      \
    float mn = fmaxf(m_q, mx);                                               \
    float alpha = exp2f(m_q - mn);                                           \
    m_q = mn;                                                                \
    float pv[4][4]; float s_ = 0.f;                                          \
    _Pragma("unroll")                                                        \
    for (int ct = 0; ct < 4; ct++)                                           \
        _Pragma("unroll")                                                    \
        for (int r_ = 0; r_ < 4; r_++) {                                     \
            pv[ct][r_] = exp2f(sacc[ct][r_] - mn);                           \
            s_ += pv[ct][r_];                                                \
        }                                                                    \
    s_ += __shfl_xor(s_, 16);                                                \
    s_ += __shfl_xor(s_, 32);                                                \
    l_q = l_q * alpha + s_;                                                  \
    if (!__all(alpha == 1.0f)) {                                             \
        _Pragma("unroll")                                                    \
        for (int ct = 0; ct < 16; ct++)                                      \
            _Pragma("unroll")                                                \
            for (int r_ = 0; r_ < 4; r_++) oacc[ct][r_] *= alpha;            \
    }                                                                        \
    unsigned int w2[4][2];                                                   \
    _Pragma("unroll")                                                        \
    for (int ct = 0; ct < 4; ct++) {                                         \
        w2[ct][0] = pkbf(pv[ct][0], pv[ct][1]);                              \
        w2[ct][1] = pkbf(pv[ct][2], pv[ct][3]);                              \
    }                                                                        \
    int sl0 = (2 * (quad & 1)) * 16 + lq;                                    \
    int sl1 = sl0 + 16;                                                      \
    bool hi = (quad >> 1) != 0;                                              \
    short8 pfrag[2];                                                         \
    _Pragma("unroll")                                                        \
    for (int kk = 0; kk < 2; kk++) {                                         \
        unsigned int u0 = __shfl((int)w2[2 * kk][0], sl0);                   \
        unsigned int u1 = __shfl((int)w2[2 * kk][1], sl0);                   \
        unsigned int u2 = __shfl((int)w2[2 * kk][0], sl1);                   \
        unsigned int u3 = __shfl((int)w2[2 * kk][1], sl1);                   \
        unsigned int v0 = __shfl((int)w2[2 * kk + 1][0], sl0);               \
        unsigned int v1 = __shfl((int)w2[2 * kk + 1][1], sl0);               \
        unsigned int v2 = __shfl((int)w2[2 * kk + 1][0], sl1);               \
        unsigned int v3 = __shfl((int)w2[2 * kk + 1][1], sl1);               \
        u32x4 pk = { hi ? v0 : u0, hi ? v1 : u1, hi ? v2 : u2, hi ? v3 : u3 }; \
        pfrag[kk] = __builtin_bit_cast(short8, pk);                          \
    }                                                                        \
    _Pragma("unroll")                                                        \
    for (int ct = 0; ct < 16; ct++) {                                        \
        int arow = ct * 16 + lq;                                             \
        short8 a0 = *(const short8*)&KVTF[arow * 64 + ((quad) ^ (arow & 7)) * 8]; \
        short8 a1 = *(const short8*)&KVTF[arow * 64 + ((4 + quad) ^ (arow & 7)) * 8]; \
        oacc[ct] = __builtin_amdgcn_mfma_f32_16x16x32_bf16(a0, pfrag[0], oacc[ct], 0, 0, 0); \
        oacc[ct] = __builtin_amdgcn_mfma_f32_16x16x32_bf16(a1, pfrag[1], oacc[ct], 0, 0, 0); \
    }                                                                        \
} while (0)

__global__ __launch_bounds__(512) void attn_kernel(const short* __restrict__ X,
                                                   const short* __restrict__ WhT,
                                                   const short* __restrict__ XT,
                                                   short* __restrict__ msgs) {
    __shared__ short kvfA[64 * 256];    // 32 KB
    __shared__ short kvfB[64 * 256];    // 32 KB
    __shared__ short kvTfA[256 * 64];   // 32 KB
    __shared__ short kvTfB[256 * 64];   // 32 KB

    int qt = blockIdx.x, bh = blockIdx.y, b = bh >> 3, h = bh & 7;
    int tid = threadIdx.x, w = tid >> 6, l = tid & 63, lq = l & 15, quad = l >> 4;
    int q0 = qt * 128;

    const short* Xb  = X  + (size_t)b * N_ * F_;
    const short* XTb = XT + (size_t)b * F_ * N_;
    const short* Whh = WhT + (size_t)h * F_ * F_;

    f32x4 oacc[16];
    short8 aq[8];

    // ---------- phase 0: Q = (X qtile @ Wh) * SCALE_QK (128 q rows) ----------
#pragma unroll
    for (int i = 0; i < 16; i++) oacc[i] = (f32x4)(0.f);
    {   // stage X rows q0..q0+127: waves 0-3 -> kvfA, waves 4-7 -> kvfB
        short* xdst = (w < 4) ? kvfA : kvfB;
        int wl = w & 3;
#pragma unroll
        for (int i = 0; i < 8; i++) {
            int r = wl * 16 + i * 2 + (l >> 5);
            int bb = (l & 31) ^ (r & 31);
            gld16(&Xb[(size_t)(q0 + ((w >> 2) * 64) + r) * F_ + bb * 8],
                  &xdst[(wl * 16 + i * 2) * 256]);
        }
    }
    const short* xsrc = (w < 4) ? kvfA : kvfB;
#pragma unroll 1
    for (int kb = 0; kb < 4; kb++) {
        __syncthreads();   // prev kb's W reads done
#pragma unroll
        for (int i = 0; i < 4; i++) {   // stage WhT[h][0:256][kb*64..+63] -> kvTfA
            int rt = w * 32 + i * 8 + (l >> 3);
            int bt = (l & 7) ^ (rt & 7);
            gld16(&Whh[(size_t)rt * F_ + kb * 64 + bt * 8], &kvTfA[(w * 32 + i * 8) * 64]);
        }
        __syncthreads();   // drains DMA (X on kb==0, W always)
#pragma unroll
        for (int kk = 0; kk < 2; kk++) {
            int arow = (w & 3) * 16 + lq;
            int ab = (kb * 8 + kk * 4 + quad) ^ (arow & 31);
            short8 af = *(const short8*)&xsrc[arow * 256 + ab * 8];
#pragma unroll
            for (int ct = 0; ct < 16; ct++) {
                int brow = ct * 16 + lq;
                int bb = (kk * 4 + quad) ^ (brow & 7);
                short8 bf = *(const short8*)&kvTfA[brow * 64 + bb * 8];
                oacc[ct] = __builtin_amdgcn_mfma_f32_16x16x32_bf16(af, bf, oacc[ct], 0, 0, 0);
            }
        }
    }
    __syncthreads();   // all W reads done; reuse kvTfA/B as Q [64 q][256 f], XOR b^(r&31)
    {
        short* qdst = (w < 4) ? kvTfA : kvTfB;
#pragma unroll
        for (int ct = 0; ct < 16; ct++) {
#pragma unroll
            for (int r = 0; r < 4; r++) {
                int row = (w & 3) * 16 + quad * 4 + r;
                int col = ct * 16 + lq;
                int pb = (col >> 3) ^ (row & 31);
                qdst[row * 256 + pb * 8 + (col & 7)] = f2bf(oacc[ct][r] * SCALE_QK);
            }
        }
        __syncthreads();
#pragma unroll
        for (int kk = 0; kk < 8; kk++) {   // aq: B-frag Q[q=(w&3)*16+lq][kk*32+quad*8..]
            int row = (w & 3) * 16 + lq;
            int ab = (kk * 4 + quad) ^ (row & 31);
            aq[kk] = *(const short8*)&qdst[row * 256 + ab * 8];
        }
    }
    __syncthreads();   // all aq reads done before tile-0 DMA overwrites kvTfA

    // ---------- phase 1: pipelined flash attention ----------
#pragma unroll
    for (int i = 0; i < 16; i++) oacc[i] = (f32x4)(0.f);
    float m_q = -INFINITY, l_q = 0.f;   // state for q = q0 + w*16 + lq

    STAGE_KV(0, kvfA, kvTfA);
    __syncthreads();   // drain tile-0 DMA

#pragma unroll 1
    for (int kt2 = 0; kt2 < 16; kt2++) {
        // half A: prefetch tile 2*kt2+1 -> B pair, compute from A pair
        STAGE_KV(2 * kt2 + 1, kvfB, kvTfB);
        COMPUTE_KT(kvfA, kvTfA);
        __syncthreads();   // all A-reads done + B-prefetch (issued pre-compute) drained
        // half B: prefetch tile (2*kt2+2)&31 -> A pair, compute from B pair
        STAGE_KV((2 * kt2 + 2) & 31, kvfA, kvTfA);   // last iter refetches tile 0 (unused, harmless)
        COMPUTE_KT(kvfB, kvTfB);
        __syncthreads();
    }

    // epilogue: per-lane q = q0 + w*16 + lq; feats ct*16 + quad*4 + r
    float inv = 1.f / l_q;
    short* Mout = msgs + (size_t)(b * N_ + q0 + w * 16 + lq) * (H_ * F_) + h * F_;
#pragma unroll
    for (int ct = 0; ct < 16; ct++) {
        s16x4 v4 = { f2bf(oacc[ct][0] * inv), f2bf(oacc[ct][1] * inv),
                     f2bf(oacc[ct][2] * inv), f2bf(oacc[ct][3] * inv) };
        *(s16x4*)&Mout[ct * 16 + quad * 4] = v4;
    }
}

extern "C" void kernel_launch(void* const* d_in, const int* in_sizes, int n_in,
                              void* d_out, int out_size, void* d_ws, size_t ws_size,
                              hipStream_t stream) {
    const float* nodes = (const float*)d_in[0];   // [4,2048,256] f32
    const float* Wh    = (const float*)d_in[1];   // [8,256,256]  f32
    const float* Wout  = (const float*)d_in[2];   // [2048,256]   f32
    const float* bias  = (const float*)d_in[3];   // [256]        f32
    float* out = (float*)d_out;                   // [4,2048,256] f32

    char* ws = (char*)d_ws;
    short* msgs   = (short*)(ws);                   // [8192][2048] bf16 = 32 MB
    short* WhT    = (short*)(ws + 33554432);        // [8][256][256]       1 MB
    short* WoutT  = (short*)(ws + 34603008);        // [256][2048]         1 MB
    short* XT     = (short*)(ws + 35651584);        // [4][256][2048]      4 MB
    short* Xbf    = (short*)(ws + 39845888);        // [4][2048][256]      4 MB
    short* biasbf = (short*)(ws + 44040192);        // [256]

    dim3 tblk(32, 8, 1);
    hipLaunchKernelGGL(cvtT_kernel, dim3(8, 8, 8),  tblk, 0, stream, Wh,    WhT,   256,  256);
    hipLaunchKernelGGL(cvtT_kernel, dim3(8, 64, 1), tblk, 0, stream, Wout,  WoutT, 2048, 256);
    hipLaunchKernelGGL(cvtT_kernel, dim3(8, 64, 4), tblk, 0, stream, nodes, XT,    2048, 256);
    hipLaunchKernelGGL(cvt_kernel,  dim3(1024), dim3(256), 0, stream, nodes, Xbf, 2097152);
    hipLaunchKernelGGL(cvt_kernel,  dim3(1),    dim3(256), 0, stream, bias, biasbf, 256);

    hipLaunchKernelGGL(attn_kernel, dim3(16, 32), dim3(512), 0, stream, Xbf, WhT, XT, msgs);
    hipLaunchKernelGGL(out_kernel,  dim3(128, 4), dim3(256), 0, stream, msgs, WoutT, biasbf, out);
}